// Round 1
// baseline (159.055 us; speedup 1.0000x reference)
//
#include <hip/hip_runtime.h>

typedef unsigned short u16;
typedef __bf16 bf16x8 __attribute__((ext_vector_type(8)));
typedef float  f32x4  __attribute__((ext_vector_type(4)));
typedef u16    u16x4  __attribute__((ext_vector_type(4)));

#define HH   16
#define DHH  64
#define SEQL 2048
#define NB   2
#define BHN  (NB * HH)   // 32

static __device__ __forceinline__ u16 f2bf(float f) {
    return __builtin_bit_cast(u16, (__bf16)f);
}

// ---------------------------------------------------------------------------
// Kernel 1: per-head QKV projection.  x[B,S,D] f32 -> Q,K bf16 [bh][S][64],
// V^T bf16 [bh][64][S].  One block = 64 rows x 1 head, 4 waves x 16 rows.
// ---------------------------------------------------------------------------
__global__ __launch_bounds__(256) void qkv_kernel(
    const float* __restrict__ x,
    const float* __restrict__ Wq, const float* __restrict__ bq,
    const float* __restrict__ Wk, const float* __restrict__ bk,
    const float* __restrict__ Wv, const float* __restrict__ bv,
    u16* __restrict__ Qws, u16* __restrict__ Kws, u16* __restrict__ Vtws)
{
    const int h   = blockIdx.y;
    const int r0  = blockIdx.x * 64;          // row in [0, B*S)
    const int tid = threadIdx.x;
    const int w   = tid >> 6;
    const int l   = tid & 63;
    const int c   = l & 15;
    const int g   = l >> 4;

    __shared__ u16 vt[64 * 72];               // V-tile transposed [d][s_local]

    // A-fragments of x for this wave's 16 rows: x[row][h*64 + kh*32 + g*8 + j]
    bf16x8 xa[2];
    {
        const float* xp = x + (size_t)(r0 + w * 16 + c) * 1024 + h * 64 + g * 8;
        #pragma unroll
        for (int kh = 0; kh < 2; ++kh) {
            float4 lo = *reinterpret_cast<const float4*>(xp + kh * 32);
            float4 hi = *reinterpret_cast<const float4*>(xp + kh * 32 + 4);
            bf16x8 f;
            f[0]=(__bf16)lo.x; f[1]=(__bf16)lo.y; f[2]=(__bf16)lo.z; f[3]=(__bf16)lo.w;
            f[4]=(__bf16)hi.x; f[5]=(__bf16)hi.y; f[6]=(__bf16)hi.z; f[7]=(__bf16)hi.w;
            xa[kh] = f;
        }
    }

    const int b      = r0 >> 11;              // / SEQL
    const int s_base = r0 & (SEQL - 1);
    const int bh     = b * HH + h;

    const float* Ws[3] = {Wq + h * 64 * 64, Wk + h * 64 * 64, Wv + h * 64 * 64};
    const float* bs[3] = {bq + h * 64,      bk + h * 64,      bv + h * 64};

    #pragma unroll
    for (int m = 0; m < 3; ++m) {
        const float* W    = Ws[m];
        const float* bias = bs[m];
        f32x4 acc[4];
        #pragma unroll
        for (int ct = 0; ct < 4; ++ct) {
            acc[ct][0] = 0.f; acc[ct][1] = 0.f; acc[ct][2] = 0.f; acc[ct][3] = 0.f;
        }
        #pragma unroll
        for (int kh = 0; kh < 2; ++kh) {
            #pragma unroll
            for (int ct = 0; ct < 4; ++ct) {
                // B-operand: B[k=d][col=e] = W[e][d] -> contiguous 8 f32 of W row
                const float* wp = W + (ct * 16 + c) * 64 + kh * 32 + g * 8;
                float4 lo = *reinterpret_cast<const float4*>(wp);
                float4 hi = *reinterpret_cast<const float4*>(wp + 4);
                bf16x8 wf;
                wf[0]=(__bf16)lo.x; wf[1]=(__bf16)lo.y; wf[2]=(__bf16)lo.z; wf[3]=(__bf16)lo.w;
                wf[4]=(__bf16)hi.x; wf[5]=(__bf16)hi.y; wf[6]=(__bf16)hi.z; wf[7]=(__bf16)hi.w;
                acc[ct] = __builtin_amdgcn_mfma_f32_16x16x32_bf16(xa[kh], wf, acc[ct], 0, 0, 0);
            }
        }
        // C layout: col(e) = c, row(s within 16) = g*4 + r
        if (m < 2) {
            u16* outp = (m == 0 ? Qws : Kws) +
                        ((size_t)bh * SEQL + s_base + w * 16 + g * 4) * 64;
            #pragma unroll
            for (int ct = 0; ct < 4; ++ct) {
                float bb = bias[ct * 16 + c];
                #pragma unroll
                for (int r = 0; r < 4; ++r)
                    outp[(size_t)r * 64 + ct * 16 + c] = f2bf(acc[ct][r] + bb);
            }
        } else {
            #pragma unroll
            for (int ct = 0; ct < 4; ++ct) {
                float bb = bias[ct * 16 + c];
                #pragma unroll
                for (int r = 0; r < 4; ++r)
                    vt[(ct * 16 + c) * 72 + w * 16 + g * 4 + r] = f2bf(acc[ct][r] + bb);
            }
        }
    }
    __syncthreads();
    {   // V^T tile [64 d][64 s] -> global, 32B chunks
        const int d  = tid >> 2;
        const int s0 = (tid & 3) * 16;
        u16* vp = Vtws + ((size_t)bh * 64 + d) * SEQL + s_base + s0;
        uint4 v0 = *reinterpret_cast<const uint4*>(&vt[d * 72 + s0]);
        uint4 v1 = *reinterpret_cast<const uint4*>(&vt[d * 72 + s0 + 8]);
        *reinterpret_cast<uint4*>(vp)     = v0;
        *reinterpret_cast<uint4*>(vp + 8) = v1;
    }
}

// ---------------------------------------------------------------------------
// Kernel 2: flash attention.  One block = 128 q-rows of one (b,h); 4 waves x
// 32 q-rows.  S^T = K*Q^T (q lane-local), online softmax, O^T = V^T*P^T.
// ---------------------------------------------------------------------------
__global__ __launch_bounds__(256) void attn_kernel(
    const u16* __restrict__ Qws, const u16* __restrict__ Kws,
    const u16* __restrict__ Vtws, float* __restrict__ out)
{
    // XCD-chunk swizzle: 512 blocks, round-robin %8 -> give each XCD 64
    // consecutive logical blocks = 4 whole heads (K/V stay in that XCD's L2).
    const int p     = blockIdx.x;
    const int lid   = (p & 7) * 64 + (p >> 3);
    const int qtile = lid & 15;
    const int bh    = lid >> 4;
    const int b     = bh >> 4;
    const int h     = bh & 15;

    const int tid = threadIdx.x;
    const int w   = tid >> 6;
    const int l   = tid & 63;
    const int c   = l & 15;
    const int g   = l >> 4;
    const int q0  = qtile * 128 + w * 32;

    __shared__ u16 plds_all[4 * 32 * 64];     // per-wave 4KB P buffer
    char* pbase = reinterpret_cast<char*>(plds_all + w * (32 * 64));

    // Q fragments (B-operand of S^T): Q[q0+qt*16+c][kh*32+g*8 ..+8]
    bf16x8 qf[2][2];
    #pragma unroll
    for (int qt = 0; qt < 2; ++qt)
        #pragma unroll
        for (int kh = 0; kh < 2; ++kh)
            qf[qt][kh] = *reinterpret_cast<const bf16x8*>(
                Qws + ((size_t)bh * SEQL + q0 + qt * 16 + c) * 64 + kh * 32 + g * 8);

    f32x4 acc[4][2];                           // O^T accum [dt][qt]
    #pragma unroll
    for (int dt = 0; dt < 4; ++dt)
        #pragma unroll
        for (int qt = 0; qt < 2; ++qt) {
            acc[dt][qt][0]=0.f; acc[dt][qt][1]=0.f; acc[dt][qt][2]=0.f; acc[dt][qt][3]=0.f;
        }
    float mrow[2] = {-1e30f, -1e30f};
    float lrow[2] = {0.f, 0.f};
    const float SCL = 0.125f * 1.44269504088896340736f;   // scale * log2(e)

    const u16* Kb = Kws  + (size_t)bh * SEQL * 64;
    const u16* Vb = Vtws + (size_t)bh * 64 * SEQL;

    for (int t = 0; t < SEQL / 64; ++t) {
        const int k0 = t * 64;

        // ---- S^T = K * Q^T : st[kt][qt], key = kt*16 + g*4 + r, q = qt*16 + c
        f32x4 st[4][2];
        #pragma unroll
        for (int kt = 0; kt < 4; ++kt)
            #pragma unroll
            for (int qt = 0; qt < 2; ++qt) {
                st[kt][qt][0]=0.f; st[kt][qt][1]=0.f; st[kt][qt][2]=0.f; st[kt][qt][3]=0.f;
            }
        #pragma unroll
        for (int kt = 0; kt < 4; ++kt) {
            const u16* kp = Kb + (size_t)(k0 + kt * 16 + c) * 64 + g * 8;
            bf16x8 ka0 = *reinterpret_cast<const bf16x8*>(kp);
            bf16x8 ka1 = *reinterpret_cast<const bf16x8*>(kp + 32);
            #pragma unroll
            for (int qt = 0; qt < 2; ++qt) {
                st[kt][qt] = __builtin_amdgcn_mfma_f32_16x16x32_bf16(ka0, qf[qt][0], st[kt][qt], 0, 0, 0);
                st[kt][qt] = __builtin_amdgcn_mfma_f32_16x16x32_bf16(ka1, qf[qt][1], st[kt][qt], 0, 0, 0);
            }
        }

        // ---- online softmax (per qt; q-row is lane-local: 16 in-lane + 2 shfl)
        #pragma unroll
        for (int qt = 0; qt < 2; ++qt) {
            float mx = st[0][qt][0];
            #pragma unroll
            for (int kt = 0; kt < 4; ++kt)
                #pragma unroll
                for (int r = 0; r < 4; ++r)
                    mx = fmaxf(mx, st[kt][qt][r]);
            mx = fmaxf(mx, __shfl_xor(mx, 16, 64));
            mx = fmaxf(mx, __shfl_xor(mx, 32, 64));
            const float mn    = fmaxf(mrow[qt], mx * SCL);
            const float alpha = __builtin_amdgcn_exp2f(mrow[qt] - mn);
            mrow[qt] = mn;

            float rs = 0.f;
            const int row = qt * 16 + c;
            #pragma unroll
            for (int kt = 0; kt < 4; ++kt) {
                u16x4 pb;
                #pragma unroll
                for (int r = 0; r < 4; ++r) {
                    float pv = __builtin_amdgcn_exp2f(fmaf(st[kt][qt][r], SCL, -mn));
                    rs += pv;
                    pb[r] = f2bf(pv);
                }
                // XOR-swizzled write: 4 bf16 (keys kt*16+g*4 ..+4) of row q
                const int blk = (kt * 2 + (g >> 1)) ^ (row & 7);
                *reinterpret_cast<u16x4*>(pbase + row * 128 + blk * 16 + (g & 1) * 8) = pb;
            }
            rs += __shfl_xor(rs, 16, 64);
            rs += __shfl_xor(rs, 32, 64);
            lrow[qt] = lrow[qt] * alpha + rs;
            #pragma unroll
            for (int dt = 0; dt < 4; ++dt) {
                acc[dt][qt][0] *= alpha; acc[dt][qt][1] *= alpha;
                acc[dt][qt][2] *= alpha; acc[dt][qt][3] *= alpha;
            }
        }

        asm volatile("s_waitcnt lgkmcnt(0)" ::: "memory");

        // ---- P fragments (B-operand of PV): P[q=c+qt*16][kh*32 + g*8 ..+8]
        bf16x8 pf[2][2];
        #pragma unroll
        for (int qt = 0; qt < 2; ++qt) {
            const int row = qt * 16 + c;
            #pragma unroll
            for (int kh = 0; kh < 2; ++kh) {
                const int blk = (kh * 4 + g) ^ (row & 7);
                pf[qt][kh] = *reinterpret_cast<const bf16x8*>(pbase + row * 128 + blk * 16);
            }
        }

        // ---- O^T += V^T * P^T : acc[dt][qt], d = dt*16 + g*4 + r, q = qt*16 + c
        #pragma unroll
        for (int dt = 0; dt < 4; ++dt) {
            const u16* vp = Vb + (size_t)(dt * 16 + c) * SEQL + k0 + g * 8;
            bf16x8 vf0 = *reinterpret_cast<const bf16x8*>(vp);
            bf16x8 vf1 = *reinterpret_cast<const bf16x8*>(vp + 32);
            #pragma unroll
            for (int qt = 0; qt < 2; ++qt) {
                acc[dt][qt] = __builtin_amdgcn_mfma_f32_16x16x32_bf16(vf0, pf[qt][0], acc[dt][qt], 0, 0, 0);
                acc[dt][qt] = __builtin_amdgcn_mfma_f32_16x16x32_bf16(vf1, pf[qt][1], acc[dt][qt], 0, 0, 0);
            }
        }
    }

    // ---- epilogue: out[b][q][h*64 + d] = O^T[d][q] / l[q]
    const float inv0 = 1.f / lrow[0];
    const float inv1 = 1.f / lrow[1];
    #pragma unroll
    for (int qt = 0; qt < 2; ++qt) {
        const float inv = qt ? inv1 : inv0;
        float* op = out + ((size_t)b * SEQL + q0 + qt * 16 + c) * 1024 + h * 64 + g * 4;
        #pragma unroll
        for (int dt = 0; dt < 4; ++dt) {
            float4 o;
            o.x = acc[dt][qt][0] * inv; o.y = acc[dt][qt][1] * inv;
            o.z = acc[dt][qt][2] * inv; o.w = acc[dt][qt][3] * inv;
            *reinterpret_cast<float4*>(op + dt * 16) = o;
        }
    }
}

extern "C" void kernel_launch(void* const* d_in, const int* in_sizes, int n_in,
                              void* d_out, int out_size, void* d_ws, size_t ws_size,
                              hipStream_t stream) {
    const float* x  = (const float*)d_in[0];
    const float* Wq = (const float*)d_in[1];
    const float* bq = (const float*)d_in[2];
    const float* Wk = (const float*)d_in[3];
    const float* bk = (const float*)d_in[4];
    const float* Wv = (const float*)d_in[5];
    const float* bv = (const float*)d_in[6];
    float* out = (float*)d_out;

    const size_t per = (size_t)BHN * SEQL * 64;   // 4Mi elems per matrix
    u16* Qws = (u16*)d_ws;
    u16* Kws = Qws + per;
    u16* Vt  = Kws + per;

    qkv_kernel<<<dim3(64, 16), 256, 0, stream>>>(x, Wq, bq, Wk, bk, Wv, bv, Qws, Kws, Vt);
    attn_kernel<<<dim3(512), 256, 0, stream>>>(Qws, Kws, Vt, out);
}